// Round 3
// baseline (897.093 us; speedup 1.0000x reference)
//
#include <hip/hip_runtime.h>

#define B_    4096
#define MDEN  13
#define NEMB  26
#define VOCAB 100000
#define NI    27
#define NPAIRS 351
#define PDIM  415
#define PPAD  416
#define BT    8
#define NT    256

// LDS strides (floats) — chosen so stride%32 == 4 (2-way max bank aliasing, free)
#define S_A 516   // 512-wide buffers
#define S_B 260   // 256-wide buffers
#define S_P 420   // 416-wide p tile
#define S_T 68    // 64-wide T rows

// ---------------- prep: pad tw0 (512 x 415) -> ws (512 x 416), pad col = 0 ----------------
__global__ void pad_tw0_kernel(const float* __restrict__ tw0, float* __restrict__ tw0p) {
    int idx = blockIdx.x * 256 + threadIdx.x;
    if (idx >= 512 * PPAD) return;
    int o = idx / PPAD, c = idx - o * PPAD;
    tw0p[idx] = (c < PDIM) ? tw0[o * PDIM + c] : 0.0f;
}

// Generic dense layer: BT rows in LDS (stride SIN) -> BT rows in LDS (stride SOUT).
// Micro-tile: each thread does 2 rows x 4 outputs; 256 threads cover 8 rows x 256 outs per pass.
template<int IN, int OUT, int SIN, int SOUT, bool RELU>
__device__ __forceinline__ void mlp_layer(const float* src, const float* __restrict__ W,
                                          const float* __restrict__ bias, float* dst, int t)
{
    const int r0 = (t & 3) * 2;
    const float* x0 = src + r0 * SIN;
    const float* x1 = x0 + SIN;
#pragma unroll
    for (int p = 0; p < OUT / 256; ++p) {
        const int o = ((t >> 2) << 2) + (p << 8);
        const float* w0 = W + (size_t)o * IN;
        const float* w1 = w0 + IN;
        const float* w2 = w1 + IN;
        const float* w3 = w2 + IN;
        float a00=0.f,a01=0.f,a02=0.f,a03=0.f,a10=0.f,a11=0.f,a12=0.f,a13=0.f;
        for (int i = 0; i < IN; i += 4) {
            float4 xa = *(const float4*)(x0 + i);
            float4 xb = *(const float4*)(x1 + i);
            float4 wa = *(const float4*)(w0 + i);
            float4 wb = *(const float4*)(w1 + i);
            float4 wc = *(const float4*)(w2 + i);
            float4 wd = *(const float4*)(w3 + i);
            a00 += xa.x*wa.x + xa.y*wa.y + xa.z*wa.z + xa.w*wa.w;
            a01 += xa.x*wb.x + xa.y*wb.y + xa.z*wb.z + xa.w*wb.w;
            a02 += xa.x*wc.x + xa.y*wc.y + xa.z*wc.z + xa.w*wc.w;
            a03 += xa.x*wd.x + xa.y*wd.y + xa.z*wd.z + xa.w*wd.w;
            a10 += xb.x*wa.x + xb.y*wa.y + xb.z*wa.z + xb.w*wa.w;
            a11 += xb.x*wb.x + xb.y*wb.y + xb.z*wb.z + xb.w*wb.w;
            a12 += xb.x*wc.x + xb.y*wc.y + xb.z*wc.z + xb.w*wc.w;
            a13 += xb.x*wd.x + xb.y*wd.y + xb.z*wd.z + xb.w*wd.w;
        }
        float4 bb = *(const float4*)(bias + o);
        float v00=a00+bb.x, v01=a01+bb.y, v02=a02+bb.z, v03=a03+bb.w;
        float v10=a10+bb.x, v11=a11+bb.y, v12=a12+bb.z, v13=a13+bb.w;
        if (RELU) {
            v00=fmaxf(v00,0.f); v01=fmaxf(v01,0.f); v02=fmaxf(v02,0.f); v03=fmaxf(v03,0.f);
            v10=fmaxf(v10,0.f); v11=fmaxf(v11,0.f); v12=fmaxf(v12,0.f); v13=fmaxf(v13,0.f);
        }
        *(float4*)(dst + r0 * SOUT + o)       = make_float4(v00,v01,v02,v03);
        *(float4*)(dst + (r0+1) * SOUT + o)   = make_float4(v10,v11,v12,v13);
    }
}

__global__ __launch_bounds__(NT, 2)
void dlrm_fused(const float* __restrict__ dense, const int* __restrict__ sidx,
                const float* __restrict__ emb,
                const float* __restrict__ bw0, const float* __restrict__ bb0,
                const float* __restrict__ bw1, const float* __restrict__ bb1,
                const float* __restrict__ bw2, const float* __restrict__ bb2,
                const float* __restrict__ tw0p, const float* __restrict__ tb0,
                const float* __restrict__ tw1, const float* __restrict__ tb1,
                const float* __restrict__ tw2, const float* __restrict__ tb2,
                float* __restrict__ out)
{
    __shared__ float xin[BT][16];
    __shared__ float bufA[BT][S_A];   // 512-wide stage buffer (h0a, then t0a)
    __shared__ float bufB[BT][S_B];   // 256-wide stage buffer (h1a, then t1a)
    __shared__ float ptile[BT][S_P];  // p rows: [0..63]=x, [64..414]=Z, [415]=0
    __shared__ float Tsh[NI][S_T];    // one row's T (27 x 64)
    __shared__ int   idxs[NEMB][BT];
    __shared__ float red[BT][36];

    const int t = threadIdx.x;
    const int brow = blockIdx.x * BT;

    // ---- preload dense rows + sparse indices; zero p pad column ----
    if (t < BT * 16) { int r = t >> 4, c = t & 15; xin[r][c] = (c < MDEN) ? dense[(brow + r) * MDEN + c] : 0.f; }
    if (t < NEMB * BT) { int j = t >> 3, r = t & 7; idxs[j][r] = sidx[j * B_ + brow + r]; }
    if (t < BT) ptile[t][PDIM] = 0.f;
    __syncthreads();

    // ---- bottom L1: 13 -> 512, relu ----
    {
        int r = t & 7, obase = (t >> 3) * 16;
        float xr[MDEN];
#pragma unroll
        for (int i = 0; i < MDEN; ++i) xr[i] = xin[r][i];
        for (int k = 0; k < 16; ++k) {
            int o = obase + k;
            const float* w = bw0 + o * MDEN;
            float acc = bb0[o];
#pragma unroll
            for (int i = 0; i < MDEN; ++i) acc += xr[i] * w[i];
            bufA[r][o] = fmaxf(acc, 0.f);
        }
    }
    __syncthreads();

    // ---- bottom L2: 512 -> 256, relu ----
    mlp_layer<512, 256, S_A, S_B, true>(&bufA[0][0], bw1, bb1, &bufB[0][0], t);
    __syncthreads();

    // ---- bottom L3: 256 -> 64, no relu -> ptile[:, 0..63] ----
    {
        int r = t & 7, o = (t >> 3) * 2;  // 2 outputs per thread
        const float* x0 = &bufB[r][0];
        const float* w0 = bw2 + o * 256;
        const float* w1 = w0 + 256;
        float a0 = 0.f, a1 = 0.f;
        for (int i = 0; i < 256; i += 4) {
            float4 xa = *(const float4*)(x0 + i);
            float4 wa = *(const float4*)(w0 + i);
            float4 wb = *(const float4*)(w1 + i);
            a0 += xa.x*wa.x + xa.y*wa.y + xa.z*wa.z + xa.w*wa.w;
            a1 += xa.x*wb.x + xa.y*wb.y + xa.z*wb.z + xa.w*wb.w;
        }
        ptile[r][o]     = a0 + bb2[o];
        ptile[r][o + 1] = a1 + bb2[o + 1];
    }
    __syncthreads();

    // ---- interaction: per row, gather T (27x64) then 351 pair dots ----
    for (int rr = 0; rr < BT; ++rr) {
        if (t < 64) Tsh[0][t] = ptile[rr][t];
        for (int e = t; e < NEMB * 64; e += NT) {
            int j = e >> 6, d = e & 63;
            int v = idxs[j][rr];
            Tsh[j + 1][d] = emb[((size_t)j * VOCAB + v) * 64 + d];
        }
        __syncthreads();
        for (int k = t; k < NPAIRS; k += NT) {
            int i = (int)((1.0f + sqrtf(8.0f * k + 1.0f)) * 0.5f);
            while (i * (i - 1) / 2 > k) --i;
            while ((i + 1) * i / 2 <= k) ++i;
            int j = k - i * (i - 1) / 2;
            const float* ti = &Tsh[i][0];
            const float* tj = &Tsh[j][0];
            float acc = 0.f;
#pragma unroll
            for (int d = 0; d < 64; d += 4) {
                float4 a = *(const float4*)(ti + d);
                float4 b = *(const float4*)(tj + d);
                acc += a.x*b.x + a.y*b.y + a.z*b.z + a.w*b.w;
            }
            ptile[rr][64 + k] = acc;
        }
        __syncthreads();
    }

    // ---- top L1: 416 -> 512, relu (pad col 415 * zero weight = 0) ----
    mlp_layer<PPAD, 512, S_P, S_A, true>(&ptile[0][0], tw0p, tb0, &bufA[0][0], t);
    __syncthreads();

    // ---- top L2: 512 -> 256, relu ----
    mlp_layer<512, 256, S_A, S_B, true>(&bufA[0][0], tw1, tb1, &bufB[0][0], t);
    __syncthreads();

    // ---- top L3: 256 -> 1 ----
    {
        int g = t >> 3, r = t & 7;       // 32 groups of 8 inputs
        const float* x = &bufB[r][0];
        int i0 = g * 8;
        float acc = 0.f;
#pragma unroll
        for (int i = i0; i < i0 + 8; i += 4) {
            float4 a = *(const float4*)(x + i);
            float4 w = *(const float4*)(tw2 + i);
            acc += a.x*w.x + a.y*w.y + a.z*w.z + a.w*w.w;
        }
        red[r][g] = acc;
    }
    __syncthreads();
    if (t < BT) {
        float s = tb2[0];
#pragma unroll
        for (int g = 0; g < 32; ++g) s += red[t][g];
        out[brow + t] = s;
    }
}

extern "C" void kernel_launch(void* const* d_in, const int* in_sizes, int n_in,
                              void* d_out, int out_size, void* d_ws, size_t ws_size,
                              hipStream_t stream) {
    (void)in_sizes; (void)n_in; (void)out_size; (void)ws_size;
    const float* dense = (const float*)d_in[0];
    const int*   sidx  = (const int*)d_in[1];   // harness delivers integer inputs as int32
    const float* emb   = (const float*)d_in[2];
    const float* bw0   = (const float*)d_in[3];
    const float* bb0   = (const float*)d_in[4];
    const float* bw1   = (const float*)d_in[5];
    const float* bb1   = (const float*)d_in[6];
    const float* bw2   = (const float*)d_in[7];
    const float* bb2   = (const float*)d_in[8];
    const float* tw0   = (const float*)d_in[9];
    const float* tb0   = (const float*)d_in[10];
    const float* tw1   = (const float*)d_in[11];
    const float* tb1   = (const float*)d_in[12];
    const float* tw2   = (const float*)d_in[13];
    const float* tb2   = (const float*)d_in[14];
    float* out  = (float*)d_out;
    float* tw0p = (float*)d_ws;   // 512*416 floats = 832 KB

    hipLaunchKernelGGL(pad_tw0_kernel, dim3((512 * PPAD + 255) / 256), dim3(256), 0, stream,
                       tw0, tw0p);
    hipLaunchKernelGGL(dlrm_fused, dim3(B_ / BT), dim3(NT), 0, stream,
                       dense, sidx, emb, bw0, bb0, bw1, bb1, bw2, bb2,
                       tw0p, tb0, tw1, tb1, tw2, tb2, out);
}